// Round 1
// baseline (567.345 us; speedup 1.0000x reference)
//
#include <hip/hip_runtime.h>

#define T_SEQ 256
#define PH  72
#define HSZ 1152
#define XRW 144          // x-tile row stride (halves): 72 dw, 72%32=8 -> frag banks spread
#define XSL (4 * XRW)    // per-t-slot stride (4 staged rows) = 576 halves = 1152 B

typedef float f32x4 __attribute__((ext_vector_type(4)));
typedef _Float16 f16x8 __attribute__((ext_vector_type(8)));

__device__ __forceinline__ float sigmoid_f(float x) {
    float e = __builtin_amdgcn_exp2f(-1.4426950408889634f * x);
    return __builtin_amdgcn_rcpf(1.0f + e);
}
__device__ __forceinline__ float tanh_f(float x) {
    float e = __builtin_amdgcn_exp2f(-2.8853900817779268f * x);
    return 2.0f * __builtin_amdgcn_rcpf(1.0f + e) - 1.0f;
}
__device__ __forceinline__ f16x8 load_frag16h(const float* wp, int n, int K, int k0) {
    const float* wf = wp + (size_t)n * K + k0;
    f16x8 h;
    #pragma unroll
    for (int j = 0; j < 8; ++j) h[j] = (_Float16)wf[j];
    return h;
}
__device__ __forceinline__ void load_frag16(const float* wp, int n, int K, int k0,
                                            f16x8& hi, f16x8& lo) {
    const float* wf = wp + (size_t)n * K + k0;
    #pragma unroll
    for (int j = 0; j < 8; ++j) {
        const float v = wf[j];
        const _Float16 h = (_Float16)v;
        hi[j] = h;
        lo[j] = (_Float16)(v - (float)h);
    }
}

#define MFMA16(a, b, c) __builtin_amdgcn_mfma_f32_16x16x32_f16(a, b, c, 0, 0, 0)

// ================= fused rec v5: proj0 folded into the recurrence =================
// 256 blocks x 512 thr (8 waves). bb = blockIdx&63, sub = blockIdx>>6.
// Real rows at tile row m = quad*4 (r=0 only): global row bb*16 + quad*4 + sub.
// Siblings (same bb) are 64 apart in blockIdx -> same XCD -> shared L2 for x.
// L1 waves (w<4): layer1, wih1 single-plane + whh1 hi/lo (24 MFMA/step).
// L0 waves: layer0 = x.wih0 (4 ks, f16 single-plane, fused; was proj0) +
//           h.whh0 hi/lo (2 ks x 2), 32 MFMA/step, + 16-t x reg-staging.
// x staged per chunk: 4 rows (row j holds global bb*16 + j*4 + sub) x 128 d x 16 t,
// double-buffered (32 slots). A-frag lane l16 reads staged row l16>>2 (real for
// l16%4==0; duplicates elsewhere feed discarded output rows r!=0).
__global__ __launch_bounds__(512, 2) void rec_fused(
    const float* __restrict__ x,
    const float* __restrict__ wih0, const float* __restrict__ whh0,
    const float* __restrict__ bih0, const float* __restrict__ bhh0,
    const float* __restrict__ wih1, const float* __restrict__ whh1,
    const float* __restrict__ bih1, const float* __restrict__ bhh1,
    const float* __restrict__ wfc,  const float* __restrict__ bfc,
    float* __restrict__ out)
{
    __shared__ _Float16 xh[32 * XSL];            // 36,864 B
    __shared__ _Float16 h0[2 * HSZ], h1[2 * HSZ];
    const int tid = threadIdx.x, lane = tid & 63, w = tid >> 6;
    const int l16 = lane & 15, quad = lane >> 4, k0 = quad * 8;
    const int wl = w & 3;
    const bool is1 = (w < 4);
    const int bb  = blockIdx.x & 63;
    const int sub = blockIdx.x >> 6;

    // the one x row this L0 wave stages (staged row index j = wl)
    const float* xrow = x + (size_t)(bb * 16 + wl * 4 + sub) * 128 * 256;

    f16x8 fX[4][4], fAh[4][2], fAl[4][2], fBh[4][2], fBl[4][2];
    float gb[4];
    #pragma unroll
    for (int g = 0; g < 4; ++g) {
        const int n = g * 64 + wl * 16 + l16;
        if (is1) {
            #pragma unroll
            for (int ks = 0; ks < 2; ++ks) {
                fAh[g][ks] = load_frag16h(wih1, n, 64, ks * 32 + k0);
                load_frag16(whh1, n, 64, ks * 32 + k0, fBh[g][ks], fBl[g][ks]);
            }
            gb[g] = bih1[n] + bhh1[n];
        } else {
            #pragma unroll
            for (int ks = 0; ks < 4; ++ks)
                fX[g][ks] = load_frag16h(wih0, n, 128, ks * 32 + k0);
            #pragma unroll
            for (int ks = 0; ks < 2; ++ks)
                load_frag16(whh0, n, 64, ks * 32 + k0, fAh[g][ks], fAl[g][ks]);
            gb[g] = bih0[n] + bhh0[n];
        }
    }
    for (int i = tid; i < 2 * HSZ; i += 512) { h0[i] = (_Float16)0.f; h1[i] = (_Float16)0.f; }
    float c = 0.f;   // the lane's single cell state (c1 for L1, c0 for L0)

    if (!is1) {      // stage chunks 0,1 (t = 0..31)
        #pragma unroll
        for (int cc = 0; cc < 2; ++cc)
            #pragma unroll
            for (int hd = 0; hd < 2; ++hd) {
                const int d = lane + hd * 64;
                const float* p = xrow + (size_t)d * 256 + cc * 16;
                float f[16];
                #pragma unroll
                for (int q = 0; q < 4; ++q) {
                    const float4 v = ((const float4*)p)[q];
                    f[q * 4 + 0] = v.x; f[q * 4 + 1] = v.y;
                    f[q * 4 + 2] = v.z; f[q * 4 + 3] = v.w;
                }
                #pragma unroll
                for (int tt = 0; tt < 16; ++tt)
                    xh[(cc * 16 + tt) * XSL + wl * XRW + d] = (_Float16)f[tt];
            }
    }
    __syncthreads();

    if (!is1) {      // prologue: layer0 t=0 (h=0): gates = x.W + b
        f16x8 ax[4];
        #pragma unroll
        for (int ks = 0; ks < 4; ++ks)
            ax[ks] = *(const f16x8*)&xh[(l16 >> 2) * XRW + ks * 32 + k0];
        f32x4 acc[4];
        #pragma unroll
        for (int g = 0; g < 4; ++g) acc[g] = (f32x4){gb[g], 0.f, 0.f, 0.f};
        #pragma unroll
        for (int g = 0; g < 4; ++g)
            #pragma unroll
            for (int ks = 0; ks < 4; ++ks)
                acc[g] = MFMA16(ax[ks], fX[g][ks], acc[g]);
        const float gi = sigmoid_f(acc[0][0]);
        const float gg = tanh_f(acc[2][0]);
        const float go = sigmoid_f(acc[3][0]);
        c = gi * gg;
        h0[(quad * 4) * PH + wl * 16 + l16] = (_Float16)(go * tanh_f(c));
    }
    __syncthreads();

    for (int t = 0; t < 255; ++t) {
        const int s0 = t & 1, s1 = s0 ^ 1;
        const int tn = t + 1;
        if (is1) {
            f16x8 ah[2], bh[2];
            #pragma unroll
            for (int ks = 0; ks < 2; ++ks) {
                ah[ks] = *(const f16x8*)&h0[s0 * HSZ + l16 * PH + ks * 32 + k0];
                bh[ks] = *(const f16x8*)&h1[s1 * HSZ + l16 * PH + ks * 32 + k0];
            }
            f32x4 acc[4];
            #pragma unroll
            for (int g = 0; g < 4; ++g)
                acc[g] = (f32x4){gb[g], 0.f, 0.f, 0.f};
            #pragma unroll
            for (int g = 0; g < 4; ++g)
                #pragma unroll
                for (int ks = 0; ks < 2; ++ks) {
                    acc[g] = MFMA16(ah[ks], fAh[g][ks], acc[g]);
                    acc[g] = MFMA16(bh[ks], fBh[g][ks], acc[g]);
                    acc[g] = MFMA16(bh[ks], fBl[g][ks], acc[g]);
                }
            const float gi = sigmoid_f(acc[0][0]);
            const float gf = sigmoid_f(acc[1][0]);
            const float gg = tanh_f(acc[2][0]);
            const float go = sigmoid_f(acc[3][0]);
            c = gf * c + gi * gg;
            h1[s0 * HSZ + (quad * 4) * PH + wl * 16 + l16] =
                (_Float16)(go * tanh_f(c));
        } else {
            // issue next-chunk x loads EARLY (fly under MFMA+activation)
            const bool do_stage = ((tn & 15) == 0) && (tn < 240);
            float4 vst[8];
            if (do_stage) {
                const int cc = (tn >> 4) + 1;
                #pragma unroll
                for (int hd = 0; hd < 2; ++hd) {
                    const float* p = xrow + (size_t)(lane + hd * 64) * 256 + cc * 16;
                    #pragma unroll
                    for (int q = 0; q < 4; ++q)
                        vst[hd * 4 + q] = ((const float4*)p)[q];
                }
            }
            const int slot = ((tn >> 4) & 1) * 16 + (tn & 15);
            f16x8 ax[4], ah[2];
            #pragma unroll
            for (int ks = 0; ks < 4; ++ks)
                ax[ks] = *(const f16x8*)&xh[slot * XSL + (l16 >> 2) * XRW + ks * 32 + k0];
            #pragma unroll
            for (int ks = 0; ks < 2; ++ks)
                ah[ks] = *(const f16x8*)&h0[s0 * HSZ + l16 * PH + ks * 32 + k0];
            f32x4 acc[4];
            #pragma unroll
            for (int g = 0; g < 4; ++g) acc[g] = (f32x4){gb[g], 0.f, 0.f, 0.f};
            #pragma unroll
            for (int g = 0; g < 4; ++g) {
                #pragma unroll
                for (int ks = 0; ks < 4; ++ks)
                    acc[g] = MFMA16(ax[ks], fX[g][ks], acc[g]);
                #pragma unroll
                for (int ks = 0; ks < 2; ++ks) {
                    acc[g] = MFMA16(ah[ks], fAh[g][ks], acc[g]);
                    acc[g] = MFMA16(ah[ks], fAl[g][ks], acc[g]);
                }
            }
            const float gi = sigmoid_f(acc[0][0]);
            const float gf = sigmoid_f(acc[1][0]);
            const float gg = tanh_f(acc[2][0]);
            const float go = sigmoid_f(acc[3][0]);
            c = gf * c + gi * gg;
            h0[s1 * HSZ + (quad * 4) * PH + wl * 16 + l16] =
                (_Float16)(go * tanh_f(c));
            if (do_stage) {   // convert + LDS-write LATE (loads have landed)
                const int cc = (tn >> 4) + 1;
                const int sb = (cc & 1) * 16;
                #pragma unroll
                for (int hd = 0; hd < 2; ++hd) {
                    const int d = lane + hd * 64;
                    #pragma unroll
                    for (int q = 0; q < 4; ++q) {
                        const float4 v = vst[hd * 4 + q];
                        const float vv[4] = {v.x, v.y, v.z, v.w};
                        #pragma unroll
                        for (int j = 0; j < 4; ++j)
                            xh[(sb + q * 4 + j) * XSL + wl * XRW + d] = (_Float16)vv[j];
                    }
                }
            }
        }
        __syncthreads();
    }

    if (is1) {   // epilogue: layer1[255] (h0 slot1, h1 slot0 -> h1 slot1)
        f16x8 ah[2], bh[2];
        #pragma unroll
        for (int ks = 0; ks < 2; ++ks) {
            ah[ks] = *(const f16x8*)&h0[HSZ + l16 * PH + ks * 32 + k0];
            bh[ks] = *(const f16x8*)&h1[l16 * PH + ks * 32 + k0];
        }
        f32x4 acc[4];
        #pragma unroll
        for (int g = 0; g < 4; ++g)
            acc[g] = (f32x4){gb[g], 0.f, 0.f, 0.f};
        #pragma unroll
        for (int g = 0; g < 4; ++g)
            #pragma unroll
            for (int ks = 0; ks < 2; ++ks) {
                acc[g] = MFMA16(ah[ks], fAh[g][ks], acc[g]);
                acc[g] = MFMA16(bh[ks], fBh[g][ks], acc[g]);
                acc[g] = MFMA16(bh[ks], fBl[g][ks], acc[g]);
            }
        const float gi = sigmoid_f(acc[0][0]);
        const float gf = sigmoid_f(acc[1][0]);
        const float gg = tanh_f(acc[2][0]);
        const float go = sigmoid_f(acc[3][0]);
        c = gf * c + gi * gg;
        h1[HSZ + (quad * 4) * PH + wl * 16 + l16] = (_Float16)(go * tanh_f(c));
    }
    __syncthreads();

    // head: row m = sel*4 (slot 1); out row = bb*16 + sel*4 + sub
    const int n   = tid & 127;
    const int sel = tid >> 7;
    float s = 0.f;
    for (int k = 0; k < 64; ++k)
        s += (float)h1[HSZ + (sel * 4) * PH + k] * wfc[n * 64 + k];
    out[(size_t)(bb * 16 + sel * 4 + sub) * 128 + n] = s + bfc[n];
}

extern "C" void kernel_launch(void* const* d_in, const int* in_sizes, int n_in,
                              void* d_out, int out_size, void* d_ws, size_t ws_size,
                              hipStream_t stream) {
    const float* x     = (const float*)d_in[0];
    const float* wih0  = (const float*)d_in[1];
    const float* whh0  = (const float*)d_in[2];
    const float* bih0  = (const float*)d_in[3];
    const float* bhh0  = (const float*)d_in[4];
    const float* wih1  = (const float*)d_in[5];
    const float* whh1  = (const float*)d_in[6];
    const float* bih1  = (const float*)d_in[7];
    const float* bhh1  = (const float*)d_in[8];
    const float* wfc   = (const float*)d_in[9];
    const float* bfc   = (const float*)d_in[10];
    float* out = (float*)d_out;

    rec_fused<<<256, 512, 0, stream>>>(x, wih0, whh0, bih0, bhh0,
                                       wih1, whh1, bih1, bhh1, wfc, bfc, out);
}

// Round 2
// 370.001 us; speedup vs baseline: 1.5334x; 1.5334x over previous
//
#include <hip/hip_runtime.h>

#define T_SEQ 256
#define PH  72
#define HSZ 1152
#define XRW 144          // x frag-tile row stride (halves): 72 dw -> spread banks
#define XSL 584          // per-t-slot stride (4*XRW + 8 pad) halves; 292 dw, %32=4

typedef float f32x4 __attribute__((ext_vector_type(4)));
typedef _Float16 f16x8 __attribute__((ext_vector_type(8)));

__device__ __forceinline__ float sigmoid_f(float x) {
    float e = __builtin_amdgcn_exp2f(-1.4426950408889634f * x);
    return __builtin_amdgcn_rcpf(1.0f + e);
}
__device__ __forceinline__ float tanh_f(float x) {
    float e = __builtin_amdgcn_exp2f(-2.8853900817779268f * x);
    return 2.0f * __builtin_amdgcn_rcpf(1.0f + e) - 1.0f;
}
__device__ __forceinline__ f16x8 load_frag16h(const float* wp, int n, int K, int k0) {
    const float* wf = wp + (size_t)n * K + k0;
    f16x8 h;
    #pragma unroll
    for (int j = 0; j < 8; ++j) h[j] = (_Float16)wf[j];
    return h;
}
__device__ __forceinline__ void load_frag16(const float* wp, int n, int K, int k0,
                                            f16x8& hi, f16x8& lo) {
    const float* wf = wp + (size_t)n * K + k0;
    #pragma unroll
    for (int j = 0; j < 8; ++j) {
        const float v = wf[j];
        const _Float16 h = (_Float16)v;
        hi[j] = h;
        lo[j] = (_Float16)(v - (float)h);
    }
}
__device__ __forceinline__ void gload16(const void* g, void* l) {
    __builtin_amdgcn_global_load_lds(
        (const __attribute__((address_space(1))) unsigned int*)g,
        (__attribute__((address_space(3))) unsigned int*)l, 16, 0, 0);
}

#define MFMA16(a, b, c) __builtin_amdgcn_mfma_f32_16x16x32_f16(a, b, c, 0, 0, 0)

// ================= fused rec v6: proj0 folded in, spill-free =================
// 256 blocks x 512 thr (8 waves). bb = blockIdx&63, sub = blockIdx>>6.
// Real rows: global row bb*16 + quad*4 + sub (4 per block; M-redundant 16x16 MFMA).
// Weight fragments OVERLAID across wave roles (single 128-VGPR union, like the
// proven 2-kernel rec): fA/fAl/fB hold
//   L1 waves (w<4): fA=wih1(hi, K=64, 2ks), fB[0..1]=whh1-hi, fB[2..3]=whh1-lo
//   L0 waves      : fA=whh0-hi, fAl=whh0-lo (K=64), fB[0..3]=wih0 f16 (K=128)
// x staging: global_load_lds f32 strip (32 KB, 1 chunk of 16 t x 4 rows x 128 d),
// issued at tn%16==0 for chunk cc+1, converted strip->f16 frag layout at tn%16==8.
// No staging registers; load->use distance = 8 barrier steps.
__global__ __launch_bounds__(512, 2) void rec_fused(
    const float* __restrict__ x,
    const float* __restrict__ wih0, const float* __restrict__ whh0,
    const float* __restrict__ bih0, const float* __restrict__ bhh0,
    const float* __restrict__ wih1, const float* __restrict__ whh1,
    const float* __restrict__ bih1, const float* __restrict__ bhh1,
    const float* __restrict__ wfc,  const float* __restrict__ bfc,
    float* __restrict__ out)
{
    __shared__ float    xs32[4 * 2048];          // 32,768 B staging strip
    __shared__ _Float16 xh[32 * XSL];            // 37,376 B x frags (f16)
    __shared__ _Float16 h0[2 * HSZ], h1[2 * HSZ];
    const int tid = threadIdx.x, lane = tid & 63, w = tid >> 6;
    const int l16 = lane & 15, quad = lane >> 4, k0 = quad * 8;
    const int wl = w & 3;
    const bool is1 = (w < 4);
    const int bb  = blockIdx.x & 63;
    const int sub = blockIdx.x >> 6;

    // the one x row this L0 wave stages (staged row index = wl)
    const float* xrow = x + (size_t)(bb * 16 + wl * 4 + sub) * 128 * 256;

    f16x8 fA[4][2], fAl[4][2], fB[4][4];
    float gb[4];
    #pragma unroll
    for (int g = 0; g < 4; ++g) {
        const int n = g * 64 + wl * 16 + l16;
        if (is1) {
            #pragma unroll
            for (int ks = 0; ks < 2; ++ks) {
                fA[g][ks] = load_frag16h(wih1, n, 64, ks * 32 + k0);
                load_frag16(whh1, n, 64, ks * 32 + k0, fB[g][ks], fB[g][2 + ks]);
            }
            gb[g] = bih1[n] + bhh1[n];
        } else {
            #pragma unroll
            for (int ks = 0; ks < 4; ++ks)
                fB[g][ks] = load_frag16h(wih0, n, 128, ks * 32 + k0);
            #pragma unroll
            for (int ks = 0; ks < 2; ++ks)
                load_frag16(whh0, n, 64, ks * 32 + k0, fA[g][ks], fAl[g][ks]);
            gb[g] = bih0[n] + bhh0[n];
        }
    }
    for (int i = tid; i < 2 * HSZ; i += 512) { h0[i] = (_Float16)0.f; h1[i] = (_Float16)0.f; }
    float c = 0.f;   // the lane's single cell state (c1 for L1, c0 for L0)

    // strip -> f16 frag-layout conversion for chunk cc (each L0 wave: own row)
    auto convert_chunk = [&](int cc) {
        const int sb = (cc & 1) * 16;
        const int tq = lane & 3;
        #pragma unroll
        for (int ib = 0; ib < 8; ++ib) {
            const float4 v = *(const float4*)&xs32[wl * 2048 + ib * 256 + lane * 4];
            const int d = ib * 16 + (lane >> 2);
            const float vv[4] = {v.x, v.y, v.z, v.w};
            #pragma unroll
            for (int j = 0; j < 4; ++j)
                xh[(sb + tq * 4 + j) * XSL + wl * XRW + d] = (_Float16)vv[j];
        }
    };
    // issue the 8 direct-to-LDS loads for chunk cc into the strip
    auto issue_chunk = [&](int cc) {
        #pragma unroll
        for (int ib = 0; ib < 8; ++ib)
            gload16(xrow + (size_t)(ib * 16 + (lane >> 2)) * 256 + cc * 16 + (lane & 3) * 4,
                    (char*)xs32 + wl * 8192 + ib * 1024);
    };

    if (!is1) issue_chunk(0);
    __syncthreads();                 // chunk0 gloads drained; h zeroed
    if (!is1) { convert_chunk(0); issue_chunk(1); }
    __syncthreads();                 // xh chunk0 visible; chunk1 drained

    if (!is1) {      // prologue: layer0 t=0 (h=0): gates = x.W + b
        f16x8 ax[4];
        #pragma unroll
        for (int ks = 0; ks < 4; ++ks)
            ax[ks] = *(const f16x8*)&xh[(l16 >> 2) * XRW + ks * 32 + k0];
        f32x4 acc[4];
        #pragma unroll
        for (int g = 0; g < 4; ++g) acc[g] = (f32x4){gb[g], 0.f, 0.f, 0.f};
        #pragma unroll
        for (int g = 0; g < 4; ++g)
            #pragma unroll
            for (int ks = 0; ks < 4; ++ks)
                acc[g] = MFMA16(ax[ks], fB[g][ks], acc[g]);
        const float gi = sigmoid_f(acc[0][0]);
        const float gg = tanh_f(acc[2][0]);
        const float go = sigmoid_f(acc[3][0]);
        c = gi * gg;
        h0[(quad * 4) * PH + wl * 16 + l16] = (_Float16)(go * tanh_f(c));
    }
    __syncthreads();

    for (int t = 0; t < 255; ++t) {
        const int s0 = t & 1, s1 = s0 ^ 1;
        const int tn = t + 1;
        if (is1) {
            f16x8 ah[2], bh[2];
            #pragma unroll
            for (int ks = 0; ks < 2; ++ks) {
                ah[ks] = *(const f16x8*)&h0[s0 * HSZ + l16 * PH + ks * 32 + k0];
                bh[ks] = *(const f16x8*)&h1[s1 * HSZ + l16 * PH + ks * 32 + k0];
            }
            f32x4 acc[4];
            #pragma unroll
            for (int g = 0; g < 4; ++g)
                acc[g] = (f32x4){gb[g], 0.f, 0.f, 0.f};
            #pragma unroll
            for (int g = 0; g < 4; ++g)
                #pragma unroll
                for (int ks = 0; ks < 2; ++ks) {
                    acc[g] = MFMA16(ah[ks], fA[g][ks], acc[g]);
                    acc[g] = MFMA16(bh[ks], fB[g][ks], acc[g]);
                    acc[g] = MFMA16(bh[ks], fB[g][2 + ks], acc[g]);
                }
            const float gi = sigmoid_f(acc[0][0]);
            const float gf = sigmoid_f(acc[1][0]);
            const float gg = tanh_f(acc[2][0]);
            const float go = sigmoid_f(acc[3][0]);
            c = gf * c + gi * gg;
            h1[s0 * HSZ + (quad * 4) * PH + wl * 16 + l16] =
                (_Float16)(go * tanh_f(c));
        } else {
            if ((tn & 15) == 0 && tn < 240)       // issue chunk cc+1 (async DMA)
                issue_chunk((tn >> 4) + 1);
            const int slot = ((tn >> 4) & 1) * 16 + (tn & 15);
            f16x8 ax[4], ah[2];
            #pragma unroll
            for (int ks = 0; ks < 4; ++ks)
                ax[ks] = *(const f16x8*)&xh[slot * XSL + (l16 >> 2) * XRW + ks * 32 + k0];
            #pragma unroll
            for (int ks = 0; ks < 2; ++ks)
                ah[ks] = *(const f16x8*)&h0[s0 * HSZ + l16 * PH + ks * 32 + k0];
            f32x4 acc[4];
            #pragma unroll
            for (int g = 0; g < 4; ++g) acc[g] = (f32x4){gb[g], 0.f, 0.f, 0.f};
            #pragma unroll
            for (int g = 0; g < 4; ++g) {
                #pragma unroll
                for (int ks = 0; ks < 4; ++ks)
                    acc[g] = MFMA16(ax[ks], fB[g][ks], acc[g]);
                #pragma unroll
                for (int ks = 0; ks < 2; ++ks) {
                    acc[g] = MFMA16(ah[ks], fA[g][ks], acc[g]);
                    acc[g] = MFMA16(ah[ks], fAl[g][ks], acc[g]);
                }
            }
            const float gi = sigmoid_f(acc[0][0]);
            const float gf = sigmoid_f(acc[1][0]);
            const float gg = tanh_f(acc[2][0]);
            const float go = sigmoid_f(acc[3][0]);
            c = gf * c + gi * gg;
            h0[s1 * HSZ + (quad * 4) * PH + wl * 16 + l16] =
                (_Float16)(go * tanh_f(c));
            if ((tn & 15) == 8 && tn < 248)       // strip landed 8 steps ago
                convert_chunk((tn >> 4) + 1);
        }
        __syncthreads();
    }

    if (is1) {   // epilogue: layer1[255] (h0 slot1, h1 slot0 -> h1 slot1)
        f16x8 ah[2], bh[2];
        #pragma unroll
        for (int ks = 0; ks < 2; ++ks) {
            ah[ks] = *(const f16x8*)&h0[HSZ + l16 * PH + ks * 32 + k0];
            bh[ks] = *(const f16x8*)&h1[l16 * PH + ks * 32 + k0];
        }
        f32x4 acc[4];
        #pragma unroll
        for (int g = 0; g < 4; ++g)
            acc[g] = (f32x4){gb[g], 0.f, 0.f, 0.f};
        #pragma unroll
        for (int g = 0; g < 4; ++g)
            #pragma unroll
            for (int ks = 0; ks < 2; ++ks) {
                acc[g] = MFMA16(ah[ks], fA[g][ks], acc[g]);
                acc[g] = MFMA16(bh[ks], fB[g][ks], acc[g]);
                acc[g] = MFMA16(bh[ks], fB[g][2 + ks], acc[g]);
            }
        const float gi = sigmoid_f(acc[0][0]);
        const float gf = sigmoid_f(acc[1][0]);
        const float gg = tanh_f(acc[2][0]);
        const float go = sigmoid_f(acc[3][0]);
        c = gf * c + gi * gg;
        h1[HSZ + (quad * 4) * PH + wl * 16 + l16] = (_Float16)(go * tanh_f(c));
    }
    __syncthreads();

    // head: row m = sel*4 (slot 1); out row = bb*16 + sel*4 + sub
    const int n   = tid & 127;
    const int sel = tid >> 7;
    float s = 0.f;
    for (int k = 0; k < 64; ++k)
        s += (float)h1[HSZ + (sel * 4) * PH + k] * wfc[n * 64 + k];
    out[(size_t)(bb * 16 + sel * 4 + sub) * 128 + n] = s + bfc[n];
}

extern "C" void kernel_launch(void* const* d_in, const int* in_sizes, int n_in,
                              void* d_out, int out_size, void* d_ws, size_t ws_size,
                              hipStream_t stream) {
    const float* x     = (const float*)d_in[0];
    const float* wih0  = (const float*)d_in[1];
    const float* whh0  = (const float*)d_in[2];
    const float* bih0  = (const float*)d_in[3];
    const float* bhh0  = (const float*)d_in[4];
    const float* wih1  = (const float*)d_in[5];
    const float* whh1  = (const float*)d_in[6];
    const float* bih1  = (const float*)d_in[7];
    const float* bhh1  = (const float*)d_in[8];
    const float* wfc   = (const float*)d_in[9];
    const float* bfc   = (const float*)d_in[10];
    float* out = (float*)d_out;

    rec_fused<<<256, 512, 0, stream>>>(x, wih0, whh0, bih0, bhh0,
                                       wih1, whh1, bih1, bhh1, wfc, bfc, out);
}